// Round 17
// baseline (5205.672 us; speedup 1.0000x reference)
//
#include <hip/hip_runtime.h>

#define BATCH   16
#define NPTS    32768
#define NPOINT  2048
#define C_FEAT  128
#define NSEG    512           // 64 Morton-consecutive points per segment
#define NTH     1024
#define NW      16

// ===========================================================================
// Round 17 = r16 (work-shared lazy FPS, 4.76ms) with a shorter serial chain:
//  (1) per-wave FULL pack reduce (all 16 waves read all 512 packs from LDS)
//      -> drops phase-2's cross-wave stage + one barrier (3 -> 2 /step).
//  (2) per-seg argmax candidate COORDS cached in LDS (cand[3][NSEG]);
//      centroid comes from LDS (~40cy) instead of a broadcast L2 load
//      (~300cy) on the serial critical path.
//  (3) initial packs (cmax=1e10, key=min origidx) make iteration 0 pick
//      point 0 naturally -- reference's deterministic start, no priming.
// Exactness invariants unchanged (r16 verified, absmax 0): skip seg only if
// r2*0.999 > cmax (exact member bbox; fp error ~4ulp << margin); update =
// r7-VERIFIED fmaf(dz,dz,fmaf(dy,dy,dx*dx)); u64 pack-max = (max cmax,
// tie -> min ORIGINAL idx) == np.argmax first-occurrence;
// scatter-order-independent.
// ws: [fps_idx 128KB @0][pts 8MB @1MB]
// ===========================================================================

__device__ __forceinline__ unsigned part4(unsigned v) {
  return (v & 1u) | ((v & 2u) << 2) | ((v & 4u) << 4) | ((v & 8u) << 6);
}
__device__ __forceinline__ int morton(float x, float y, float z) {
  const unsigned qx = (unsigned)min(15, max(0, (int)((x + 4.0f) * 2.0f)));
  const unsigned qy = (unsigned)min(15, max(0, (int)((y + 4.0f) * 2.0f)));
  const unsigned qz = (unsigned)min(15, max(0, (int)((z + 4.0f) * 2.0f)));
  return (int)(part4(qx) | (part4(qy) << 1) | (part4(qz) << 2));
}

__device__ __forceinline__ unsigned long long u64max(unsigned long long a,
                                                     unsigned long long b) {
  return a > b ? a : b;
}

// ---------------------------------------------------------------------------
// Morton counting sort: pts[pos] = (x,y,z,bitcast(origidx)) in sorted order.
// ---------------------------------------------------------------------------
__global__ __launch_bounds__(NTH) void sort_kernel(
    const float* __restrict__ xyz, float4* __restrict__ pts) {
  const int b = blockIdx.x, t = threadIdx.x, lane = t & 63;
  const float* __restrict__ base = xyz + (size_t)b * NPTS * 3;
  __shared__ unsigned bins[4096];
  __shared__ unsigned wsum[NW];

  for (int i = t; i < 4096; i += NTH) bins[i] = 0u;
  __syncthreads();
  for (int k = 0; k < 32; ++k) {
    const int p = k * NTH + t;
    atomicAdd(&bins[morton(base[p*3], base[p*3+1], base[p*3+2])], 1u);
  }
  __syncthreads();

  unsigned c0 = bins[4*t], c1 = bins[4*t+1], c2 = bins[4*t+2], c3 = bins[4*t+3];
  const unsigned mysum = c0 + c1 + c2 + c3;
  unsigned acc = mysum;
#pragma unroll
  for (int d = 1; d < 64; d <<= 1) {
    unsigned n = __shfl_up(acc, d);
    if (lane >= d) acc += n;
  }
  if (lane == 63) wsum[t >> 6] = acc;
  __syncthreads();
  unsigned woff = 0;
  for (int w = 0; w < (t >> 6); ++w) woff += wsum[w];
  unsigned run = woff + acc - mysum;
  bins[4*t]   = run; run += c0;
  bins[4*t+1] = run; run += c1;
  bins[4*t+2] = run; run += c2;
  bins[4*t+3] = run;
  __syncthreads();

  float4* __restrict__ pb = pts + (size_t)b * NPTS;
  for (int k = 0; k < 32; ++k) {
    const int p = k * NTH + t;
    const float x = base[p*3], y = base[p*3+1], z = base[p*3+2];
    const unsigned pos = atomicAdd(&bins[morton(x, y, z)], 1u);
    pb[pos] = make_float4(x, y, z, __int_as_float(p));
  }
}

// ---------------------------------------------------------------------------
// Work-shared lazy FPS, 2 barriers/step. One block per batch.
// ---------------------------------------------------------------------------
__global__ __launch_bounds__(NTH) void fps_kernel(
    const float4* __restrict__ pts_g, int* __restrict__ fps_idx) {
  const int b = blockIdx.x, t = threadIdx.x, lane = t & 63, w = t >> 6;
  const float4* __restrict__ P = pts_g + (size_t)b * NPTS;

  __shared__ float              dmin[NPTS];      // 128 KB
  __shared__ float              sb[6][NSEG];     // 12 KB bboxes
  __shared__ float              cand[3][NSEG];   // 6 KB argmax-candidate xyz
  __shared__ unsigned long long pack[NSEG];      // 4 KB
  __shared__ unsigned short     wl[NSEG];        // 1 KB
  __shared__ int                s_cnt[2];

  // ---- init: dmin, per-seg exact bbox, initial pack + candidate ----
  for (int r = 0; r < 32; ++r) {
    const int seg = w * 32 + r;
    const int i = seg * 64 + lane;
    const float4 q = P[i];
    dmin[i] = 1e10f;
    const unsigned mykey =
        ((unsigned)__float_as_int(q.w) << 15) | (unsigned)i;
    float xl = q.x, xh = q.x, yl = q.y, yh = q.y, zl = q.z, zh = q.z;
    unsigned k = mykey;
#pragma unroll
    for (int off = 32; off > 0; off >>= 1) {
      xl = fminf(xl, __shfl_xor(xl, off)); xh = fmaxf(xh, __shfl_xor(xh, off));
      yl = fminf(yl, __shfl_xor(yl, off)); yh = fmaxf(yh, __shfl_xor(yh, off));
      zl = fminf(zl, __shfl_xor(zl, off)); zh = fmaxf(zh, __shfl_xor(zh, off));
      k  = min(k, (unsigned)__shfl_xor((int)k, off));
    }
    if (lane == 0) {
      sb[0][seg] = xl; sb[1][seg] = xh;
      sb[2][seg] = yl; sb[3][seg] = yh;
      sb[4][seg] = zl; sb[5][seg] = zh;
      pack[seg] = ((unsigned long long)__float_as_uint(1e10f) << 32) |
                  (unsigned long long)(0x3FFFFFFFu - k);
    }
    if (mykey == k) {   // unique lane: candidate coords for this seg
      cand[0][seg] = q.x; cand[1][seg] = q.y; cand[2][seg] = q.z;
    }
  }
  if (t == 0) { s_cnt[0] = 0; s_cnt[1] = 0; }
  __syncthreads();

  for (int s = 0; s < NPOINT; ++s) {
    // ---- phase A (no barrier needed): every wave reduces all 512 packs ----
    unsigned long long p = pack[lane];
#pragma unroll
    for (int j = 1; j < 8; ++j) p = u64max(p, pack[lane + j * 64]);
#pragma unroll
    for (int off = 32; off > 0; off >>= 1) {
      const unsigned lo = (unsigned)p, hi = (unsigned)(p >> 32);
      const unsigned olo = (unsigned)__shfl_xor((int)lo, off);
      const unsigned ohi = (unsigned)__shfl_xor((int)hi, off);
      p = u64max(p, ((unsigned long long)ohi << 32) | olo);
    }
    const unsigned kwin = 0x3FFFFFFFu - (unsigned)(p & 0x3FFFFFFFu);
    const int far  = (int)(kwin >> 15);
    const int segw = (int)((kwin & 0x7FFFu) >> 6);
    const float cx = cand[0][segw], cy = cand[1][segw], cz = cand[2][segw];

    if (t == 0) fps_idx[b * NPOINT + s] = far;
    if (t == NTH - 1) s_cnt[(s + 1) & 1] = 0;   // reset other-parity slot

    // ---- phase B: predicate + compact (threads 0..511; r16-proven form) ---
    if (t < NSEG) {
      const unsigned long long pk = pack[t];
      const float cm = __uint_as_float((unsigned)(pk >> 32));
      const float ddx = fmaxf(fmaxf(sb[0][t] - cx, cx - sb[1][t]), 0.0f);
      const float ddy = fmaxf(fmaxf(sb[2][t] - cy, cy - sb[3][t]), 0.0f);
      const float ddz = fmaxf(fmaxf(sb[4][t] - cz, cz - sb[5][t]), 0.0f);
      const float r2 = ddx * ddx + ddy * ddy + ddz * ddz;
      const bool need = !(r2 * 0.999f > cm);
      const unsigned long long bal = __ballot(need);        // all lanes
      int wb = 0;
      if (lane == 0 && bal != 0ull)
        wb = atomicAdd(&s_cnt[s & 1], (int)__popcll(bal));
      wb = __shfl(wb, 0);                                   // all lanes active
      if (need) {
        const unsigned long long ltm = (1ull << lane) - 1ull;
        wl[wb + (int)__popcll(bal & ltm)] = (unsigned short)t;
      }
    }
    __syncthreads();                                          // B1

    // ---- phase C: ALL 16 waves co-scan the needy segs (dense body) ----
    const int C = s_cnt[s & 1];
    for (int e = w; e < C; e += NW) {
      const int seg = (int)wl[e];
      const int i = seg * 64 + lane;
      const float4 q = P[i];                    // coalesced 1KB/wave
      const float dx = q.x - cx, dy = q.y - cy, dz = q.z - cz;
      // EXACT reference pipeline (verified round 7):
      const float d = __builtin_fmaf(dz, dz, __builtin_fmaf(dy, dy, dx * dx));
      const float nd = fminf(dmin[i], d);
      dmin[i] = nd;                             // 2 lanes/bank: conflict-free
      float vm = nd;
      const unsigned mykey =
          ((unsigned)__float_as_int(q.w) << 15) | (unsigned)i;
      unsigned bk = mykey;
#pragma unroll
      for (int off = 32; off > 0; off >>= 1) {
        const float    ov  = __shfl_xor(vm, off);
        const unsigned obk = (unsigned)__shfl_xor((int)bk, off);
        if (ov > vm || (ov == vm && obk < bk)) { vm = ov; bk = obk; }
      }
      if (lane == 0)
        pack[seg] = ((unsigned long long)__float_as_uint(vm) << 32) |
                    (unsigned long long)(0x3FFFFFFFu - bk);
      if (mykey == bk) {  // unique lane holds the winning point's coords
        cand[0][seg] = q.x; cand[1][seg] = q.y; cand[2][seg] = q.z;
      }
    }
    __syncthreads();                                          // B2
  }
}

// ---------------------------------------------------------------------------
// Gather: [B][NPOINT][3] then [B][NPOINT][128], concatenated flat.
// ---------------------------------------------------------------------------
__global__ __launch_bounds__(256) void gather_kernel(
    const float* __restrict__ xyz, const float* __restrict__ feat,
    const int* __restrict__ fps_idx, float* __restrict__ out) {
  const int lane = threadIdx.x & 31;
  const int sub  = threadIdx.x >> 5;
  const int row  = blockIdx.x * 8 + sub;
  const int b    = row >> 11;
  const int src  = fps_idx[row];

  const float4* __restrict__ f =
      reinterpret_cast<const float4*>(feat + ((size_t)b * NPTS + src) * C_FEAT);
  float4* __restrict__ o =
      reinterpret_cast<float4*>(out + (size_t)BATCH * NPOINT * 3 +
                                (size_t)row * C_FEAT);
  o[lane] = f[lane];
  if (lane < 3) {
    out[(size_t)row * 3 + lane] = xyz[((size_t)b * NPTS + src) * 3 + lane];
  }
}

extern "C" void kernel_launch(void* const* d_in, const int* in_sizes, int n_in,
                              void* d_out, int out_size, void* d_ws, size_t ws_size,
                              hipStream_t stream) {
  (void)in_sizes; (void)n_in; (void)out_size; (void)ws_size;
  const float* xyz  = (const float*)d_in[0];
  const float* feat = (const float*)d_in[1];
  float* out = (float*)d_out;

  char* ws = (char*)d_ws;
  int*    fps_idx = (int*)ws;                     // 128 KB @ 0
  float4* pts     = (float4*)(ws + (1u << 20));   // 8 MB  @ 1MB

  sort_kernel<<<BATCH, NTH, 0, stream>>>(xyz, pts);
  fps_kernel<<<BATCH, NTH, 0, stream>>>(pts, fps_idx);
  gather_kernel<<<(BATCH * NPOINT) / 8, 256, 0, stream>>>(xyz, feat, fps_idx, out);
}

// Round 18
// 4371.934 us; speedup vs baseline: 1.1907x; 1.1907x over previous
//
#include <hip/hip_runtime.h>

#define BATCH   16
#define NPTS    32768
#define NPOINT  2048
#define C_FEAT  128
#define NSEG    512           // 64 Morton-consecutive points per segment
#define NTH     1024
#define NW      16

// ===========================================================================
// Round 18 = r16 (best, 4.76ms) + three measured-cost cuts:
//  (1) winner coords from cand[] LDS (~40cy) instead of serial L2 broadcast
//      (~250cy) -- r17's good half.
//  (2) phase-C argmax pre-packed as monotone u64 BEFORE the 6-stage wave
//      reduce (u64max ~4 instr/stage vs ~7 for (val,key) compare-select).
//  (3) 2-way manual unroll of the needy-seg loop: 2 L2 loads in flight/wave.
// Reduce stays TWO-STAGE (r17 lesson: per-wave full 512-pack reduce costs
// more than the barrier it saves). 3 barriers/step. Combine at top-of-step
// fed by s_red (stage-1 run once at init).
// Exactness invariants unchanged (r16 verified, absmax 0): skip seg only if
// r2*0.999 > cmax (exact member bbox; fp err ~4ulp << margin); update =
// r7-VERIFIED fmaf(dz,dz,fmaf(dy,dy,dx*dx)); u64 pack-max = (max cmax,
// tie -> min ORIGINAL idx) == np.argmax first-occurrence;
// scatter-order-independent.
// ws: [fps_idx 128KB @0][pts 8MB @1MB]
// ===========================================================================

__device__ __forceinline__ unsigned part4(unsigned v) {
  return (v & 1u) | ((v & 2u) << 2) | ((v & 4u) << 4) | ((v & 8u) << 6);
}
__device__ __forceinline__ int morton(float x, float y, float z) {
  const unsigned qx = (unsigned)min(15, max(0, (int)((x + 4.0f) * 2.0f)));
  const unsigned qy = (unsigned)min(15, max(0, (int)((y + 4.0f) * 2.0f)));
  const unsigned qz = (unsigned)min(15, max(0, (int)((z + 4.0f) * 2.0f)));
  return (int)(part4(qx) | (part4(qy) << 1) | (part4(qz) << 2));
}

__device__ __forceinline__ unsigned long long u64max(unsigned long long a,
                                                     unsigned long long b) {
  return a > b ? a : b;
}
__device__ __forceinline__ unsigned long long shflxor_u64(
    unsigned long long v, int off) {
  const unsigned lo = (unsigned)v, hi = (unsigned)(v >> 32);
  const unsigned olo = (unsigned)__shfl_xor((int)lo, off);
  const unsigned ohi = (unsigned)__shfl_xor((int)hi, off);
  return ((unsigned long long)ohi << 32) | olo;
}

// ---------------------------------------------------------------------------
// Morton counting sort: pts[pos] = (x,y,z,bitcast(origidx)) in sorted order.
// ---------------------------------------------------------------------------
__global__ __launch_bounds__(NTH) void sort_kernel(
    const float* __restrict__ xyz, float4* __restrict__ pts) {
  const int b = blockIdx.x, t = threadIdx.x, lane = t & 63;
  const float* __restrict__ base = xyz + (size_t)b * NPTS * 3;
  __shared__ unsigned bins[4096];
  __shared__ unsigned wsum[NW];

  for (int i = t; i < 4096; i += NTH) bins[i] = 0u;
  __syncthreads();
  for (int k = 0; k < 32; ++k) {
    const int p = k * NTH + t;
    atomicAdd(&bins[morton(base[p*3], base[p*3+1], base[p*3+2])], 1u);
  }
  __syncthreads();

  unsigned c0 = bins[4*t], c1 = bins[4*t+1], c2 = bins[4*t+2], c3 = bins[4*t+3];
  const unsigned mysum = c0 + c1 + c2 + c3;
  unsigned acc = mysum;
#pragma unroll
  for (int d = 1; d < 64; d <<= 1) {
    unsigned n = __shfl_up(acc, d);
    if (lane >= d) acc += n;
  }
  if (lane == 63) wsum[t >> 6] = acc;
  __syncthreads();
  unsigned woff = 0;
  for (int w = 0; w < (t >> 6); ++w) woff += wsum[w];
  unsigned run = woff + acc - mysum;
  bins[4*t]   = run; run += c0;
  bins[4*t+1] = run; run += c1;
  bins[4*t+2] = run; run += c2;
  bins[4*t+3] = run;
  __syncthreads();

  float4* __restrict__ pb = pts + (size_t)b * NPTS;
  for (int k = 0; k < 32; ++k) {
    const int p = k * NTH + t;
    const float x = base[p*3], y = base[p*3+1], z = base[p*3+2];
    const unsigned pos = atomicAdd(&bins[morton(x, y, z)], 1u);
    pb[pos] = make_float4(x, y, z, __int_as_float(p));
  }
}

// ---------------------------------------------------------------------------
// Work-shared lazy FPS. One block per batch; 3 barriers/step.
// ---------------------------------------------------------------------------
__global__ __launch_bounds__(NTH) void fps_kernel(
    const float4* __restrict__ pts_g, int* __restrict__ fps_idx) {
  const int b = blockIdx.x, t = threadIdx.x, lane = t & 63, w = t >> 6;
  const float4* __restrict__ P = pts_g + (size_t)b * NPTS;

  __shared__ float              dmin[NPTS];      // 128 KB
  __shared__ float              sb[6][NSEG];     // 12 KB bboxes
  __shared__ float              cand[3][NSEG];   // 6 KB argmax-candidate xyz
  __shared__ unsigned long long pack[NSEG];      // 4 KB
  __shared__ unsigned long long s_red[2][8];     // 128 B
  __shared__ unsigned short     wl[NSEG];        // 1 KB
  __shared__ int                s_cnt[2];

  // ---- init: dmin, per-seg exact bbox, initial pack + candidate ----
  for (int r = 0; r < 32; ++r) {
    const int seg = w * 32 + r;
    const int i = seg * 64 + lane;
    const float4 q = P[i];
    dmin[i] = 1e10f;
    const unsigned mykey = ((unsigned)__float_as_int(q.w) << 15) | (unsigned)i;
    float xl = q.x, xh = q.x, yl = q.y, yh = q.y, zl = q.z, zh = q.z;
    unsigned k = mykey;
#pragma unroll
    for (int off = 32; off > 0; off >>= 1) {
      xl = fminf(xl, __shfl_xor(xl, off)); xh = fmaxf(xh, __shfl_xor(xh, off));
      yl = fminf(yl, __shfl_xor(yl, off)); yh = fmaxf(yh, __shfl_xor(yh, off));
      zl = fminf(zl, __shfl_xor(zl, off)); zh = fmaxf(zh, __shfl_xor(zh, off));
      k  = min(k, (unsigned)__shfl_xor((int)k, off));
    }
    if (lane == 0) {
      sb[0][seg] = xl; sb[1][seg] = xh;
      sb[2][seg] = yl; sb[3][seg] = yh;
      sb[4][seg] = zl; sb[5][seg] = zh;
      pack[seg] = ((unsigned long long)__float_as_uint(1e10f) << 32) |
                  (unsigned long long)(0x3FFFFFFFu - k);
    }
    if (mykey == k) {   // unique lane: candidate coords for this seg
      cand[0][seg] = q.x; cand[1][seg] = q.y; cand[2][seg] = q.z;
    }
  }
  if (t == 0) { s_cnt[0] = 0; s_cnt[1] = 0; }
  __syncthreads();

  // stage-1 reduce once so step 0's combine sees valid s_red[0]
  if (t < NSEG) {
    unsigned long long p = pack[t];
#pragma unroll
    for (int off = 32; off > 0; off >>= 1) p = u64max(p, shflxor_u64(p, off));
    if (lane == 0) s_red[0][w] = p;
  }
  __syncthreads();

  for (int s = 0; s < NPOINT; ++s) {
    // ---- combine: 8 u64 from s_red (all threads, cheap) ----
    unsigned long long p = s_red[s & 1][0];
#pragma unroll
    for (int j = 1; j < 8; ++j) p = u64max(p, s_red[s & 1][j]);
    const unsigned kwin = 0x3FFFFFFFu - (unsigned)(p & 0x3FFFFFFFu);
    const int far  = (int)(kwin >> 15);
    const int segw = (int)((kwin & 0x7FFFu) >> 6);
    const float cx = cand[0][segw], cy = cand[1][segw], cz = cand[2][segw];

    if (t == 0) fps_idx[b * NPOINT + s] = far;
    if (t == NTH - 1) s_cnt[(s + 1) & 1] = 0;   // reset other-parity slot

    // ---- phase B: predicate + compact (threads 0..511; r16-proven form) ---
    if (t < NSEG) {
      const unsigned long long pk = pack[t];
      const float cm = __uint_as_float((unsigned)(pk >> 32));
      const float ddx = fmaxf(fmaxf(sb[0][t] - cx, cx - sb[1][t]), 0.0f);
      const float ddy = fmaxf(fmaxf(sb[2][t] - cy, cy - sb[3][t]), 0.0f);
      const float ddz = fmaxf(fmaxf(sb[4][t] - cz, cz - sb[5][t]), 0.0f);
      const float r2 = ddx * ddx + ddy * ddy + ddz * ddz;
      const bool need = !(r2 * 0.999f > cm);
      const unsigned long long bal = __ballot(need);        // all lanes
      int wb = 0;
      if (lane == 0 && bal != 0ull)
        wb = atomicAdd(&s_cnt[s & 1], (int)__popcll(bal));
      wb = __shfl(wb, 0);                                   // all lanes active
      if (need) {
        const unsigned long long ltm = (1ull << lane) - 1ull;
        wl[wb + (int)__popcll(bal & ltm)] = (unsigned short)t;
      }
    }
    __syncthreads();                                          // B1

    // ---- phase C: all 16 waves co-scan needy segs; 2-way unrolled ----
    const int C = s_cnt[s & 1];
    int e = w;
    for (; e + NW < C; e += 2 * NW) {
      const int segA = (int)wl[e], segB = (int)wl[e + NW];
      const int iA = segA * 64 + lane, iB = segB * 64 + lane;
      const float4 qA = P[iA];                 // 2 loads in flight
      const float4 qB = P[iB];
      const float dmA = dmin[iA], dmB = dmin[iB];
      const float dxA = qA.x - cx, dyA = qA.y - cy, dzA = qA.z - cz;
      const float dxB = qB.x - cx, dyB = qB.y - cy, dzB = qB.z - cz;
      // EXACT reference pipeline (verified round 7):
      const float dA = __builtin_fmaf(dzA, dzA, __builtin_fmaf(dyA, dyA, dxA*dxA));
      const float dB = __builtin_fmaf(dzB, dzB, __builtin_fmaf(dyB, dyB, dxB*dxB));
      const float ndA = fminf(dmA, dA), ndB = fminf(dmB, dB);
      dmin[iA] = ndA; dmin[iB] = ndB;
      const unsigned kA = ((unsigned)__float_as_int(qA.w) << 15) | (unsigned)iA;
      const unsigned kB = ((unsigned)__float_as_int(qB.w) << 15) | (unsigned)iB;
      unsigned long long pA = ((unsigned long long)__float_as_uint(ndA) << 32) |
                              (unsigned long long)(0x3FFFFFFFu - kA);
      unsigned long long pB = ((unsigned long long)__float_as_uint(ndB) << 32) |
                              (unsigned long long)(0x3FFFFFFFu - kB);
      const unsigned long long pA0 = pA, pB0 = pB;
#pragma unroll
      for (int off = 32; off > 0; off >>= 1) {
        pA = u64max(pA, shflxor_u64(pA, off));
        pB = u64max(pB, shflxor_u64(pB, off));
      }
      if (lane == 0) { pack[segA] = pA; pack[segB] = pB; }
      if (pA0 == pA) { cand[0][segA] = qA.x; cand[1][segA] = qA.y; cand[2][segA] = qA.z; }
      if (pB0 == pB) { cand[0][segB] = qB.x; cand[1][segB] = qB.y; cand[2][segB] = qB.z; }
    }
    for (; e < C; e += NW) {
      const int seg = (int)wl[e];
      const int i = seg * 64 + lane;
      const float4 q = P[i];
      const float dx = q.x - cx, dy = q.y - cy, dz = q.z - cz;
      const float d = __builtin_fmaf(dz, dz, __builtin_fmaf(dy, dy, dx * dx));
      const float nd = fminf(dmin[i], d);
      dmin[i] = nd;
      const unsigned k = ((unsigned)__float_as_int(q.w) << 15) | (unsigned)i;
      unsigned long long pk = ((unsigned long long)__float_as_uint(nd) << 32) |
                              (unsigned long long)(0x3FFFFFFFu - k);
      const unsigned long long pk0 = pk;
#pragma unroll
      for (int off = 32; off > 0; off >>= 1) pk = u64max(pk, shflxor_u64(pk, off));
      if (lane == 0) pack[seg] = pk;
      if (pk0 == pk) { cand[0][seg] = q.x; cand[1][seg] = q.y; cand[2][seg] = q.z; }
    }
    __syncthreads();                                          // B2

    // ---- stage 1: 512 threads -> s_red[(s+1)&1][8] ----
    if (t < NSEG) {
      unsigned long long pk = pack[t];
#pragma unroll
      for (int off = 32; off > 0; off >>= 1) pk = u64max(pk, shflxor_u64(pk, off));
      if (lane == 0) s_red[(s + 1) & 1][w] = pk;
    }
    __syncthreads();                                          // B3
  }
}

// ---------------------------------------------------------------------------
// Gather: [B][NPOINT][3] then [B][NPOINT][128], concatenated flat.
// ---------------------------------------------------------------------------
__global__ __launch_bounds__(256) void gather_kernel(
    const float* __restrict__ xyz, const float* __restrict__ feat,
    const int* __restrict__ fps_idx, float* __restrict__ out) {
  const int lane = threadIdx.x & 31;
  const int sub  = threadIdx.x >> 5;
  const int row  = blockIdx.x * 8 + sub;
  const int b    = row >> 11;
  const int src  = fps_idx[row];

  const float4* __restrict__ f =
      reinterpret_cast<const float4*>(feat + ((size_t)b * NPTS + src) * C_FEAT);
  float4* __restrict__ o =
      reinterpret_cast<float4*>(out + (size_t)BATCH * NPOINT * 3 +
                                (size_t)row * C_FEAT);
  o[lane] = f[lane];
  if (lane < 3) {
    out[(size_t)row * 3 + lane] = xyz[((size_t)b * NPTS + src) * 3 + lane];
  }
}

extern "C" void kernel_launch(void* const* d_in, const int* in_sizes, int n_in,
                              void* d_out, int out_size, void* d_ws, size_t ws_size,
                              hipStream_t stream) {
  (void)in_sizes; (void)n_in; (void)out_size; (void)ws_size;
  const float* xyz  = (const float*)d_in[0];
  const float* feat = (const float*)d_in[1];
  float* out = (float*)d_out;

  char* ws = (char*)d_ws;
  int*    fps_idx = (int*)ws;                     // 128 KB @ 0
  float4* pts     = (float4*)(ws + (1u << 20));   // 8 MB  @ 1MB

  sort_kernel<<<BATCH, NTH, 0, stream>>>(xyz, pts);
  fps_kernel<<<BATCH, NTH, 0, stream>>>(pts, fps_idx);
  gather_kernel<<<(BATCH * NPOINT) / 8, 256, 0, stream>>>(xyz, feat, fps_idx, out);
}

// Round 19
// 3830.091 us; speedup vs baseline: 1.3592x; 1.1415x over previous
//
#include <hip/hip_runtime.h>

#define BATCH   16
#define NPTS    32768
#define NPOINT  2048
#define C_FEAT  128
#define NSEG    1024          // 32 Morton-consecutive points per segment
#define NTH     1024
#define NW      16

// ===========================================================================
// Round 19 = r18 (4.37ms) with 32-pt half-wave segments:
//  - seg reduce: 5 stages (was 6), two segs per wave in parallel (+2-way
//    unroll = 4 reduce chains in flight) -> phase C latency cut.
//  - finer prune shell: updated points per step ~halve.
//  - phase B predicate on ALL 16 waves (1024 segs <-> 1024 threads).
//  - LDS fit: bbox = f32 center + bf16 ROUND-UP extent (conservative:
//    enclosing bbox => smaller r2 => never skips what f32 bbox wouldn't;
//    exactness needs only conservatism, margin 0.999 >> fp noise).
//    cand[] dropped; winner centroid via one broadcast L2 load.
// Exactness invariants unchanged (r16/r18 verified, absmax 0): skip seg only
// if r2*0.999 > cmax; update = r7-VERIFIED fmaf(dz,dz,fmaf(dy,dy,dx*dx));
// u64 pack-max = (max cmax, tie -> min ORIGINAL idx) == np.argmax
// first-occurrence; scatter-order-independent.
// ws: [fps_idx 128KB @0][pts 8MB @1MB]
// ===========================================================================

__device__ __forceinline__ unsigned part4(unsigned v) {
  return (v & 1u) | ((v & 2u) << 2) | ((v & 4u) << 4) | ((v & 8u) << 6);
}
__device__ __forceinline__ int morton(float x, float y, float z) {
  const unsigned qx = (unsigned)min(15, max(0, (int)((x + 4.0f) * 2.0f)));
  const unsigned qy = (unsigned)min(15, max(0, (int)((y + 4.0f) * 2.0f)));
  const unsigned qz = (unsigned)min(15, max(0, (int)((z + 4.0f) * 2.0f)));
  return (int)(part4(qx) | (part4(qy) << 1) | (part4(qz) << 2));
}

__device__ __forceinline__ unsigned long long u64max(unsigned long long a,
                                                     unsigned long long b) {
  return a > b ? a : b;
}
__device__ __forceinline__ unsigned long long shflxor_u64(
    unsigned long long v, int off) {
  const unsigned lo = (unsigned)v, hi = (unsigned)(v >> 32);
  const unsigned olo = (unsigned)__shfl_xor((int)lo, off);
  const unsigned ohi = (unsigned)__shfl_xor((int)hi, off);
  return ((unsigned long long)ohi << 32) | olo;
}
// bf16 round-UP for positive floats (conservative extent)
__device__ __forceinline__ unsigned short bfup(float e) {
  const unsigned u = __float_as_uint(e);
  unsigned short b = (unsigned short)(u >> 16);
  if (__uint_as_float(((unsigned)b) << 16) < e) ++b;
  return b;
}

// ---------------------------------------------------------------------------
// Morton counting sort: pts[pos] = (x,y,z,bitcast(origidx)) in sorted order.
// ---------------------------------------------------------------------------
__global__ __launch_bounds__(NTH) void sort_kernel(
    const float* __restrict__ xyz, float4* __restrict__ pts) {
  const int b = blockIdx.x, t = threadIdx.x, lane = t & 63;
  const float* __restrict__ base = xyz + (size_t)b * NPTS * 3;
  __shared__ unsigned bins[4096];
  __shared__ unsigned wsum[NW];

  for (int i = t; i < 4096; i += NTH) bins[i] = 0u;
  __syncthreads();
  for (int k = 0; k < 32; ++k) {
    const int p = k * NTH + t;
    atomicAdd(&bins[morton(base[p*3], base[p*3+1], base[p*3+2])], 1u);
  }
  __syncthreads();

  unsigned c0 = bins[4*t], c1 = bins[4*t+1], c2 = bins[4*t+2], c3 = bins[4*t+3];
  const unsigned mysum = c0 + c1 + c2 + c3;
  unsigned acc = mysum;
#pragma unroll
  for (int d = 1; d < 64; d <<= 1) {
    unsigned n = __shfl_up(acc, d);
    if (lane >= d) acc += n;
  }
  if (lane == 63) wsum[t >> 6] = acc;
  __syncthreads();
  unsigned woff = 0;
  for (int w = 0; w < (t >> 6); ++w) woff += wsum[w];
  unsigned run = woff + acc - mysum;
  bins[4*t]   = run; run += c0;
  bins[4*t+1] = run; run += c1;
  bins[4*t+2] = run; run += c2;
  bins[4*t+3] = run;
  __syncthreads();

  float4* __restrict__ pb = pts + (size_t)b * NPTS;
  for (int k = 0; k < 32; ++k) {
    const int p = k * NTH + t;
    const float x = base[p*3], y = base[p*3+1], z = base[p*3+2];
    const unsigned pos = atomicAdd(&bins[morton(x, y, z)], 1u);
    pb[pos] = make_float4(x, y, z, __int_as_float(p));
  }
}

// ---------------------------------------------------------------------------
// Work-shared lazy FPS, 32-pt half-wave segments. One block per batch.
// ---------------------------------------------------------------------------
__global__ __launch_bounds__(NTH) void fps_kernel(
    const float4* __restrict__ pts_g, int* __restrict__ fps_idx) {
  const int b = blockIdx.x, t = threadIdx.x, lane = t & 63, w = t >> 6;
  const int hw = t >> 5, hl = t & 31;            // 32 half-waves of 32 lanes
  const float4* __restrict__ P = pts_g + (size_t)b * NPTS;

  __shared__ float              dmin[NPTS];      // 128 KB
  __shared__ unsigned long long pack[NSEG];      // 8 KB
  __shared__ float              cenx[NSEG], ceny[NSEG], cenz[NSEG];  // 12 KB
  __shared__ unsigned short     extx[NSEG], exty[NSEG], extz[NSEG];  // 6 KB
  __shared__ unsigned long long s_red[2][8];     // 128 B
  __shared__ unsigned short     wl[NSEG];        // 2 KB
  __shared__ int                s_cnt[2];

  // ---- init: dmin, per-seg bbox (center + bf16-up extent), pack ----
  for (int r = 0; r < 32; ++r) {
    const int seg = r * 32 + hw;
    const int i = seg * 32 + hl;
    const float4 q = P[i];
    dmin[i] = 1e10f;
    float xl = q.x, xh = q.x, yl = q.y, yh = q.y, zl = q.z, zh = q.z;
    unsigned k = ((unsigned)__float_as_int(q.w) << 15) | (unsigned)i;
#pragma unroll
    for (int off = 16; off > 0; off >>= 1) {
      xl = fminf(xl, __shfl_xor(xl, off)); xh = fmaxf(xh, __shfl_xor(xh, off));
      yl = fminf(yl, __shfl_xor(yl, off)); yh = fmaxf(yh, __shfl_xor(yh, off));
      zl = fminf(zl, __shfl_xor(zl, off)); zh = fmaxf(zh, __shfl_xor(zh, off));
      k  = min(k, (unsigned)__shfl_xor((int)k, off));
    }
    if (hl == 0) {
      const float cxm = 0.5f * (xl + xh);
      const float cym = 0.5f * (yl + yh);
      const float czm = 0.5f * (zl + zh);
      // extent: f32 +2ulp nudge then bf16 round-up => provably enclosing
      float ex = fmaxf(xh - cxm, cxm - xl);
      float ey = fmaxf(yh - cym, cym - yl);
      float ez = fmaxf(zh - czm, czm - zl);
      ex = __uint_as_float(__float_as_uint(ex) + 2);
      ey = __uint_as_float(__float_as_uint(ey) + 2);
      ez = __uint_as_float(__float_as_uint(ez) + 2);
      cenx[seg] = cxm; ceny[seg] = cym; cenz[seg] = czm;
      extx[seg] = bfup(ex); exty[seg] = bfup(ey); extz[seg] = bfup(ez);
      pack[seg] = ((unsigned long long)__float_as_uint(1e10f) << 32) |
                  (unsigned long long)(0x3FFFFFFFu - k);
    }
  }
  if (t == 0) { s_cnt[0] = 0; s_cnt[1] = 0; }
  __syncthreads();

  // initial stage-1 so step 0's combine sees valid s_red[0]
  if (t < 512) {
    unsigned long long p = u64max(pack[t], pack[t + 512]);
#pragma unroll
    for (int off = 32; off > 0; off >>= 1) p = u64max(p, shflxor_u64(p, off));
    if (lane == 0) s_red[0][w] = p;
  }
  __syncthreads();

  for (int s = 0; s < NPOINT; ++s) {
    // ---- combine + winner centroid (broadcast L2 load) ----
    unsigned long long p = s_red[s & 1][0];
#pragma unroll
    for (int j = 1; j < 8; ++j) p = u64max(p, s_red[s & 1][j]);
    const unsigned kwin = 0x3FFFFFFFu - (unsigned)(p & 0x3FFFFFFFu);
    const int far = (int)(kwin >> 15);
    const float4 qn = P[(int)(kwin & 0x7FFFu)];
    const float cx = qn.x, cy = qn.y, cz = qn.z;

    if (t == 0) fps_idx[b * NPOINT + s] = far;
    if (t == NTH - 1) s_cnt[(s + 1) & 1] = 0;

    // ---- phase B: predicate on ALL 1024 threads (seg = t) + compact ----
    {
      const unsigned long long pk = pack[t];
      const float cm = __uint_as_float((unsigned)(pk >> 32));
      const float ex = __uint_as_float(((unsigned)extx[t]) << 16);
      const float ey = __uint_as_float(((unsigned)exty[t]) << 16);
      const float ez = __uint_as_float(((unsigned)extz[t]) << 16);
      const float ddx = fmaxf(fabsf(cx - cenx[t]) - ex, 0.0f);
      const float ddy = fmaxf(fabsf(cy - ceny[t]) - ey, 0.0f);
      const float ddz = fmaxf(fabsf(cz - cenz[t]) - ez, 0.0f);
      const float r2 = ddx * ddx + ddy * ddy + ddz * ddz;
      const bool need = !(r2 * 0.999f > cm);
      const unsigned long long bal = __ballot(need);
      int wb = 0;
      if (lane == 0 && bal != 0ull)
        wb = atomicAdd(&s_cnt[s & 1], (int)__popcll(bal));
      wb = __shfl(wb, 0);
      if (need) {
        const unsigned long long ltm = (1ull << lane) - 1ull;
        wl[wb + (int)__popcll(bal & ltm)] = (unsigned short)t;
      }
    }
    __syncthreads();                                          // B1

    // ---- phase C: 32 half-waves co-scan needy segs; 2-way unrolled ----
    const int C = s_cnt[s & 1];
    int e = hw;
    for (; e + 32 < C; e += 64) {
      const int segA = (int)wl[e], segB = (int)wl[e + 32];
      const int iA = segA * 32 + hl, iB = segB * 32 + hl;
      const float4 qA = P[iA];
      const float4 qB = P[iB];
      const float dmA = dmin[iA], dmB = dmin[iB];
      const float dxA = qA.x - cx, dyA = qA.y - cy, dzA = qA.z - cz;
      const float dxB = qB.x - cx, dyB = qB.y - cy, dzB = qB.z - cz;
      // EXACT reference pipeline (verified round 7):
      const float dA = __builtin_fmaf(dzA, dzA, __builtin_fmaf(dyA, dyA, dxA*dxA));
      const float dB = __builtin_fmaf(dzB, dzB, __builtin_fmaf(dyB, dyB, dxB*dxB));
      const float ndA = fminf(dmA, dA), ndB = fminf(dmB, dB);
      dmin[iA] = ndA; dmin[iB] = ndB;
      const unsigned kA = ((unsigned)__float_as_int(qA.w) << 15) | (unsigned)iA;
      const unsigned kB = ((unsigned)__float_as_int(qB.w) << 15) | (unsigned)iB;
      unsigned long long pA = ((unsigned long long)__float_as_uint(ndA) << 32) |
                              (unsigned long long)(0x3FFFFFFFu - kA);
      unsigned long long pB = ((unsigned long long)__float_as_uint(ndB) << 32) |
                              (unsigned long long)(0x3FFFFFFFu - kB);
#pragma unroll
      for (int off = 16; off > 0; off >>= 1) {
        pA = u64max(pA, shflxor_u64(pA, off));
        pB = u64max(pB, shflxor_u64(pB, off));
      }
      if (hl == 0) { pack[segA] = pA; pack[segB] = pB; }
    }
    for (; e < C; e += 32) {
      const int seg = (int)wl[e];
      const int i = seg * 32 + hl;
      const float4 q = P[i];
      const float dx = q.x - cx, dy = q.y - cy, dz = q.z - cz;
      const float d = __builtin_fmaf(dz, dz, __builtin_fmaf(dy, dy, dx * dx));
      const float nd = fminf(dmin[i], d);
      dmin[i] = nd;
      const unsigned k = ((unsigned)__float_as_int(q.w) << 15) | (unsigned)i;
      unsigned long long pk = ((unsigned long long)__float_as_uint(nd) << 32) |
                              (unsigned long long)(0x3FFFFFFFu - k);
#pragma unroll
      for (int off = 16; off > 0; off >>= 1) pk = u64max(pk, shflxor_u64(pk, off));
      if (hl == 0) pack[seg] = pk;
    }
    __syncthreads();                                          // B2

    // ---- stage 1: 512 threads reduce 1024 packs -> s_red[(s+1)&1][8] ----
    if (t < 512) {
      unsigned long long pk = u64max(pack[t], pack[t + 512]);
#pragma unroll
      for (int off = 32; off > 0; off >>= 1) pk = u64max(pk, shflxor_u64(pk, off));
      if (lane == 0) s_red[(s + 1) & 1][w] = pk;
    }
    __syncthreads();                                          // B3
  }
}

// ---------------------------------------------------------------------------
// Gather: [B][NPOINT][3] then [B][NPOINT][128], concatenated flat.
// ---------------------------------------------------------------------------
__global__ __launch_bounds__(256) void gather_kernel(
    const float* __restrict__ xyz, const float* __restrict__ feat,
    const int* __restrict__ fps_idx, float* __restrict__ out) {
  const int lane = threadIdx.x & 31;
  const int sub  = threadIdx.x >> 5;
  const int row  = blockIdx.x * 8 + sub;
  const int b    = row >> 11;
  const int src  = fps_idx[row];

  const float4* __restrict__ f =
      reinterpret_cast<const float4*>(feat + ((size_t)b * NPTS + src) * C_FEAT);
  float4* __restrict__ o =
      reinterpret_cast<float4*>(out + (size_t)BATCH * NPOINT * 3 +
                                (size_t)row * C_FEAT);
  o[lane] = f[lane];
  if (lane < 3) {
    out[(size_t)row * 3 + lane] = xyz[((size_t)b * NPTS + src) * 3 + lane];
  }
}

extern "C" void kernel_launch(void* const* d_in, const int* in_sizes, int n_in,
                              void* d_out, int out_size, void* d_ws, size_t ws_size,
                              hipStream_t stream) {
  (void)in_sizes; (void)n_in; (void)out_size; (void)ws_size;
  const float* xyz  = (const float*)d_in[0];
  const float* feat = (const float*)d_in[1];
  float* out = (float*)d_out;

  char* ws = (char*)d_ws;
  int*    fps_idx = (int*)ws;                     // 128 KB @ 0
  float4* pts     = (float4*)(ws + (1u << 20));   // 8 MB  @ 1MB

  sort_kernel<<<BATCH, NTH, 0, stream>>>(xyz, pts);
  fps_kernel<<<BATCH, NTH, 0, stream>>>(pts, fps_idx);
  gather_kernel<<<(BATCH * NPOINT) / 8, 256, 0, stream>>>(xyz, feat, fps_idx, out);
}